// Round 6
// baseline (241.866 us; speedup 1.0000x reference)
//
#include <hip/hip_runtime.h>
#include <hip/hip_bf16.h>

#define NPB 64                 // nodes per transform block
#define CH_BITS 9
#define CH_NODES 512           // nodes per chunk
#define BIN_T 4096             // edges per hist/bin block
#define MAX_CHUNK_EDGES 8192   // mean 6531, sd ~81 -> +20 sigma headroom

// f32 -> bf16 round-to-nearest-even (finite values)
__device__ __forceinline__ unsigned short f2b(float f) {
    unsigned int u = __float_as_uint(f);
    u += 0x7fffu + ((u >> 16) & 1u);
    return (unsigned short)(u >> 16);
}
__device__ __forceinline__ float b2f_lo(unsigned int u) { return __uint_as_float(u << 16); }
__device__ __forceinline__ float b2f_hi(unsigned int u) { return __uint_as_float(u & 0xffff0000u); }

// Block-wide (256 thr) inclusive scan via wave shfl + 4-entry LDS scratch.
// Contains one __syncthreads(); caller must sync before reusing wsum.
__device__ __forceinline__ int block_scan_incl256(int v, int t, int* wsum) {
    int incl = v;
    #pragma unroll
    for (int o = 1; o < 64; o <<= 1) {
        const int u = __shfl_up(incl, o, 64);
        if ((t & 63) >= o) incl += u;
    }
    const int wid = t >> 6;
    if ((t & 63) == 63) wsum[wid] = incl;
    __syncthreads();
    int base = 0;
    #pragma unroll
    for (int wj = 0; wj < 3; ++wj)
        if (wj < wid) base += wsum[wj];
    return base + incl;
}

// K1: chunk histogram (LDS-aggregated) + last-block ticket does the 196-wide
// exclusive scan -> chunk_base/chunk_cursor. One dispatch instead of two.
__global__ __launch_bounds__(256) void gcn_hist_scan_kernel(
    const int* __restrict__ dst, int* __restrict__ chunk_cnt, int* __restrict__ done,
    int* __restrict__ chunk_base, int* __restrict__ chunk_cursor,
    int n_edges, int nchunk, int nblocks)
{
    __shared__ int h[256];
    __shared__ int wsum[4];
    __shared__ int amlast;
    const int t = threadIdx.x;
    h[t] = 0;
    __syncthreads();

    const int blo = blockIdx.x * BIN_T;
    if (blo + BIN_T <= n_edges) {
        const int4* d4 = (const int4*)(dst + blo);
        #pragma unroll
        for (int k = 0; k < BIN_T / 1024; ++k) {
            const int4 dd = d4[k * 256 + t];
            atomicAdd(&h[dd.x >> CH_BITS], 1);
            atomicAdd(&h[dd.y >> CH_BITS], 1);
            atomicAdd(&h[dd.z >> CH_BITS], 1);
            atomicAdd(&h[dd.w >> CH_BITS], 1);
        }
    } else {
        for (int e = blo + t; e < n_edges; e += 256)
            atomicAdd(&h[dst[e] >> CH_BITS], 1);
    }
    __syncthreads();
    if (t < nchunk && h[t] > 0) atomicAdd(&chunk_cnt[t], h[t]);

    __threadfence();
    if (t == 0) amlast = (atomicAdd(done, 1) == nblocks - 1);
    __syncthreads();
    if (!amlast) return;

    // last block: coherent read of counts, exclusive scan
    const int v = (t < nchunk) ? atomicAdd(&chunk_cnt[t], 0) : 0;
    const int incl = block_scan_incl256(v, t, wsum);
    const int excl = incl - v;
    if (t <= nchunk) chunk_base[t] = excl;     // chunk_base[nchunk] == n_edges
    if (t < nchunk)  chunk_cursor[t] = excl;
}

// K2 (fused): blocks [0,bblocks) bin edges into chunk regions (LDS-grouped
// coalesced writes); blocks [bblocks,...) do the dense transform:
//   yb[n]    = bf16( x[n] @ W_lin^T )
//   selfb[n] = bf16( x[n] @ W_self^T + b_lin + b_self + bias )
// Transform reads x via wave-uniform global loads (scalar path) -> no xs LDS.
__global__ __launch_bounds__(256) void gcn_bin_transform_kernel(
    const int* __restrict__ src, const int* __restrict__ dst,
    int* __restrict__ chunk_cursor, int* __restrict__ bin_edges,
    const float* __restrict__ x,
    const float* __restrict__ W_lin,  const float* __restrict__ b_lin,
    const float* __restrict__ W_self, const float* __restrict__ b_self,
    const float* __restrict__ bias,
    unsigned short* __restrict__ yb, unsigned short* __restrict__ selfb,
    int n_nodes, int n_edges, int bblocks)
{
    __shared__ __align__(16) char smem[32768];   // union of both branches
    const int t = threadIdx.x;

    if ((int)blockIdx.x < bblocks) {
        // ---------------- binning branch (<= 24.6 KB) ----------------
        int*           stage = (int*)smem;                        // [4096]
        unsigned char* cidx  = (unsigned char*)(smem + 16384);    // [4096]
        int*           h     = (int*)(smem + 20480);              // [256]
        int*           loff  = (int*)(smem + 21504);              // [256]
        int*           rc    = (int*)(smem + 22528);              // [256]
        int*           gbase = (int*)(smem + 23552);              // [256]
        int*           wsum  = (int*)(smem + 24576);              // [4]

        h[t] = 0; rc[t] = 0;
        __syncthreads();

        const int blo = blockIdx.x * BIN_T;
        const int cnt = min(BIN_T, n_edges - blo);

        int myc[16], mypk[16];
        #pragma unroll
        for (int k = 0; k < 16; ++k) {
            const int e = blo + k * 256 + t;
            if (e < n_edges) {
                const int d = dst[e];
                myc[k]  = d >> CH_BITS;
                mypk[k] = ((d & (CH_NODES - 1)) << 17) | src[e];
                atomicAdd(&h[myc[k]], 1);
            } else myc[k] = -1;
        }
        __syncthreads();

        const int v = h[t];
        if (v > 0) gbase[t] = atomicAdd(&chunk_cursor[t], v);   // reserve
        const int incl = block_scan_incl256(v, t, wsum);
        loff[t] = incl - v;
        __syncthreads();

        #pragma unroll
        for (int k = 0; k < 16; ++k) {
            if (myc[k] >= 0) {
                const int p   = atomicAdd(&rc[myc[k]], 1);
                const int pos = loff[myc[k]] + p;
                stage[pos] = mypk[k];
                cidx[pos]  = (unsigned char)myc[k];
            }
        }
        __syncthreads();

        for (int i = t; i < cnt; i += 256) {      // contiguous runs per chunk
            const int c = cidx[i];
            bin_edges[gbase[c] + (i - loff[c])] = stage[i];
        }
        return;
    }

    // ---------------- transform branch (32 KB weights) ----------------
    float4* w4 = (float4*)smem;     // [0,1024): W_lin [f4][o]; [1024,2048): W_self
    for (int q = t; q < 1024; q += 256) {
        const int o = q & 63, f4 = q >> 6;
        w4[q]        = *(const float4*)&W_lin [o * 64 + f4 * 4];
        w4[1024 + q] = *(const float4*)&W_self[o * 64 + f4 * 4];
    }
    __syncthreads();

    const int o = t & 63;                                   // out feature
    const int w = __builtin_amdgcn_readfirstlane(t >> 6);   // wave id (uniform)
    const int node0 = ((int)blockIdx.x - bblocks) * NPB;
    const float bsum = b_lin[o] + b_self[o] + bias[o];

    float acc_y[16], acc_o[16];
    #pragma unroll
    for (int j = 0; j < 16; ++j) { acc_y[j] = 0.f; acc_o[j] = bsum; }

    const float* xw = x + (long long)(node0 + w) * 64;      // wave-uniform base
    for (int f4 = 0; f4 < 16; ++f4) {
        const float4 wl  = w4[f4 * 64 + o];
        const float4 wsf = w4[1024 + f4 * 64 + o];
        #pragma unroll
        for (int j = 0; j < 16; ++j) {
            float4 xv;
            if (node0 + w + j * 4 < n_nodes)                 // uniform branch
                xv = *(const float4*)&xw[j * 256 + f4 * 4];  // uniform address
            else
                xv = make_float4(0.f, 0.f, 0.f, 0.f);
            acc_y[j] += xv.x * wl.x  + xv.y * wl.y  + xv.z * wl.z  + xv.w * wl.w;
            acc_o[j] += xv.x * wsf.x + xv.y * wsf.y + xv.z * wsf.z + xv.w * wsf.w;
        }
    }
    #pragma unroll
    for (int j = 0; j < 16; ++j) {
        const int n = node0 + w + j * 4;
        if (n < n_nodes) {
            yb   [(long long)n * 64 + o] = f2b(acc_y[j]);
            selfb[(long long)n * 64 + o] = f2b(acc_o[j]);
        }
    }
}

// K3: per-chunk counting sort (in place) + node_start emission.
__global__ __launch_bounds__(256) void gcn_chunk_sort_kernel(
    int* __restrict__ bin_edges,             // in: packed; out: plain src
    const int* __restrict__ chunk_base,
    int* __restrict__ node_start, int n_nodes, int n_edges)
{
    __shared__ int stage[MAX_CHUNK_EDGES];   // 32 KB
    __shared__ int off[CH_NODES];            // 2 KB
    __shared__ int cur[CH_NODES];            // 2 KB
    __shared__ int wsum[4];

    const int b = blockIdx.x, t = threadIdx.x;
    const int lo  = chunk_base[b];
    const int cnt = min(chunk_base[b + 1] - lo, MAX_CHUNK_EDGES);

    for (int i = t; i < cnt; i += 256) stage[i] = bin_edges[lo + i];
    off[t] = 0; off[t + 256] = 0;
    __syncthreads();

    for (int i = t; i < cnt; i += 256) atomicAdd(&off[stage[i] >> 17], 1);
    __syncthreads();

    const int a0 = off[2 * t], a1 = off[2 * t + 1];
    const int incl = block_scan_incl256(a0 + a1, t, wsum);
    const int pexcl = incl - (a0 + a1);
    __syncthreads();
    off[2 * t] = pexcl;          off[2 * t + 1] = pexcl + a0;
    cur[2 * t] = pexcl;          cur[2 * t + 1] = pexcl + a0;

    const int n0 = b << CH_BITS;
    if (n0 + 2 * t     < n_nodes) node_start[n0 + 2 * t]     = lo + pexcl;
    if (n0 + 2 * t + 1 < n_nodes) node_start[n0 + 2 * t + 1] = lo + pexcl + a0;
    if (b == 0 && t == 0) node_start[n_nodes] = n_edges;
    __syncthreads();

    for (int i = t; i < cnt; i += 256) {
        const int p = stage[i];
        const int pos = atomicAdd(&cur[p >> 17], 1);
        bin_edges[lo + pos] = p & 0x1FFFF;
    }
}

// K4: per-node segment sum over bf16 y rows. One wave per node; 4 lane-groups
// of 16 x unroll 4 -> 16 edges (4 independent row gathers) in flight per iter.
__global__ __launch_bounds__(256) void gcn_aggregate_kernel(
    const int* __restrict__ sorted_src, const int* __restrict__ node_start,
    const unsigned short* __restrict__ yb, const unsigned short* __restrict__ selfb,
    float* __restrict__ out, int n_nodes)
{
    const int node = ((int)blockIdx.x * 256 + threadIdx.x) >> 6;
    if (node >= n_nodes) return;
    const int lane = threadIdx.x & 63;
    const int grp = lane >> 4, sub = lane & 15;

    const int lo  = node_start[node];
    const int cnt = node_start[node + 1] - lo;

    float ax = 0.f, ay = 0.f, az = 0.f, aw = 0.f;
    for (int i = 0; i < cnt; i += 16) {
        bool val[4]; uint2 d[4];
        #pragma unroll
        for (int j = 0; j < 4; ++j) {
            const int k = i + grp + 4 * j;
            val[j] = k < cnt;
            const int s = val[j] ? sorted_src[lo + k] : 0;
            d[j] = *(const uint2*)(yb + ((long long)s << 6) + (sub << 2));
        }
        #pragma unroll
        for (int j = 0; j < 4; ++j) {
            if (val[j]) {
                ax += b2f_lo(d[j].x); ay += b2f_hi(d[j].x);
                az += b2f_lo(d[j].y); aw += b2f_hi(d[j].y);
            }
        }
    }
    ax += __shfl_xor(ax, 16); ay += __shfl_xor(ay, 16);
    az += __shfl_xor(az, 16); aw += __shfl_xor(aw, 16);
    ax += __shfl_xor(ax, 32); ay += __shfl_xor(ay, 32);
    az += __shfl_xor(az, 32); aw += __shfl_xor(aw, 32);

    if (grp == 0) {
        const uint2 sv = *(const uint2*)(selfb + ((long long)node << 6) + (sub << 2));
        float4 o;
        o.x = ax + b2f_lo(sv.x); o.y = ay + b2f_hi(sv.x);
        o.z = az + b2f_lo(sv.y); o.w = aw + b2f_hi(sv.y);
        *(float4*)(out + ((long long)node << 6) + (sub << 2)) = o;
    }
}

extern "C" void kernel_launch(void* const* d_in, const int* in_sizes, int n_in,
                              void* d_out, int out_size, void* d_ws, size_t ws_size,
                              hipStream_t stream) {
    const float* x      = (const float*)d_in[0];
    const int*   src    = (const int*)  d_in[1];
    const int*   dst    = (const int*)  d_in[2];
    const float* W_lin  = (const float*)d_in[3];
    const float* b_lin  = (const float*)d_in[4];
    const float* W_self = (const float*)d_in[5];
    const float* b_self = (const float*)d_in[6];
    const float* bias   = (const float*)d_in[7];

    float* out = (float*)d_out;

    const int n_nodes = in_sizes[0] / 64;
    const int n_edges = in_sizes[1];
    const int nchunk  = (n_nodes + CH_NODES - 1) >> CH_BITS;   // 196

    // ws layout: yb | selfb | bin_edges | node_start | chunk_cnt | done | chunk_base | chunk_cursor
    char* wsp = (char*)d_ws;
    unsigned short* yb    = (unsigned short*)wsp;                         // N*64 bf16
    unsigned short* selfb = (unsigned short*)(wsp + (size_t)n_nodes * 64 * 2);
    int* bin_edges    = (int*)(wsp + (size_t)n_nodes * 64 * 4);           // E i32
    int* node_start   = bin_edges + n_edges;                              // N+1 i32
    int* chunk_cnt    = node_start + n_nodes + 1;                         // 256
    int* done         = chunk_cnt + 256;                                  // 4 (pad)
    int* chunk_base   = done + 4;                                         // 257
    int* chunk_cursor = chunk_base + 257;                                 // 256

    const int hblocks = (n_edges + BIN_T - 1) / BIN_T;   // 313
    const int tblocks = (n_nodes + NPB - 1) / NPB;       // 1563

    hipMemsetAsync(chunk_cnt, 0, 260 * 4, stream);       // chunk_cnt + done
    gcn_hist_scan_kernel<<<hblocks, 256, 0, stream>>>(
        dst, chunk_cnt, done, chunk_base, chunk_cursor, n_edges, nchunk, hblocks);
    gcn_bin_transform_kernel<<<hblocks + tblocks, 256, 0, stream>>>(
        src, dst, chunk_cursor, bin_edges,
        x, W_lin, b_lin, W_self, b_self, bias,
        yb, selfb, n_nodes, n_edges, hblocks);
    gcn_chunk_sort_kernel<<<nchunk, 256, 0, stream>>>(
        bin_edges, chunk_base, node_start, n_nodes, n_edges);
    gcn_aggregate_kernel<<<(n_nodes + 3) / 4, 256, 0, stream>>>(
        bin_edges, node_start, yb, selfb, out, n_nodes);
}

// Round 7
// 201.546 us; speedup vs baseline: 1.2001x; 1.2001x over previous
//
#include <hip/hip_runtime.h>
#include <hip/hip_bf16.h>

#define NPB_T 256              // nodes per transform block (4 waves x 64)
#define CH_BITS 9
#define CH_NODES 512           // nodes per chunk
#define BIN_T 4096             // edges per hist/bin block
#define MAX_CHUNK_EDGES 8192   // mean 6531, sd ~81

typedef __attribute__((ext_vector_type(8))) short  short8;   // 8 bf16 (4 VGPR)
typedef __attribute__((ext_vector_type(4))) float  f32x4;    // MFMA acc

// f32 -> bf16 round-to-nearest-even (finite values)
__device__ __forceinline__ unsigned short f2b(float f) {
    unsigned int u = __float_as_uint(f);
    u += 0x7fffu + ((u >> 16) & 1u);
    return (unsigned short)(u >> 16);
}
__device__ __forceinline__ float b2f_lo(unsigned int u) { return __uint_as_float(u << 16); }
__device__ __forceinline__ float b2f_hi(unsigned int u) { return __uint_as_float(u & 0xffff0000u); }

// Load 8 consecutive f32 and pack to a bf16 A/B fragment (16 B along f).
__device__ __forceinline__ short8 frag8(const float* p) {
    const float4 p0 = *(const float4*)p;
    const float4 p1 = *(const float4*)(p + 4);
    short8 r;
    r[0] = (short)f2b(p0.x); r[1] = (short)f2b(p0.y);
    r[2] = (short)f2b(p0.z); r[3] = (short)f2b(p0.w);
    r[4] = (short)f2b(p1.x); r[5] = (short)f2b(p1.y);
    r[6] = (short)f2b(p1.z); r[7] = (short)f2b(p1.w);
    return r;
}

// Block-wide (256 thr) inclusive scan via wave shfl + 4-entry LDS scratch.
__device__ __forceinline__ int block_scan_incl256(int v, int t, int* wsum) {
    int incl = v;
    #pragma unroll
    for (int o = 1; o < 64; o <<= 1) {
        const int u = __shfl_up(incl, o, 64);
        if ((t & 63) >= o) incl += u;
    }
    const int wid = t >> 6;
    if ((t & 63) == 63) wsum[wid] = incl;
    __syncthreads();
    int base = 0;
    #pragma unroll
    for (int wj = 0; wj < 3; ++wj)
        if (wj < wid) base += wsum[wj];
    return base + incl;
}

// K1: chunk histogram (LDS-aggregated) + last-block ticket does the 196-wide
// exclusive scan -> chunk_base/chunk_cursor.
__global__ __launch_bounds__(256) void gcn_hist_scan_kernel(
    const int* __restrict__ dst, int* __restrict__ chunk_cnt, int* __restrict__ done,
    int* __restrict__ chunk_base, int* __restrict__ chunk_cursor,
    int n_edges, int nchunk, int nblocks)
{
    __shared__ int h[256];
    __shared__ int wsum[4];
    __shared__ int amlast;
    const int t = threadIdx.x;
    h[t] = 0;
    __syncthreads();

    const int blo = blockIdx.x * BIN_T;
    if (blo + BIN_T <= n_edges) {
        const int4* d4 = (const int4*)(dst + blo);
        #pragma unroll
        for (int k = 0; k < BIN_T / 1024; ++k) {
            const int4 dd = d4[k * 256 + t];
            atomicAdd(&h[dd.x >> CH_BITS], 1);
            atomicAdd(&h[dd.y >> CH_BITS], 1);
            atomicAdd(&h[dd.z >> CH_BITS], 1);
            atomicAdd(&h[dd.w >> CH_BITS], 1);
        }
    } else {
        for (int e = blo + t; e < n_edges; e += 256)
            atomicAdd(&h[dst[e] >> CH_BITS], 1);
    }
    __syncthreads();
    if (t < nchunk && h[t] > 0) atomicAdd(&chunk_cnt[t], h[t]);

    __threadfence();
    if (t == 0) amlast = (atomicAdd(done, 1) == nblocks - 1);
    __syncthreads();
    if (!amlast) return;

    const int v = (t < nchunk) ? atomicAdd(&chunk_cnt[t], 0) : 0;
    const int incl = block_scan_incl256(v, t, wsum);
    const int excl = incl - v;
    if (t <= nchunk) chunk_base[t] = excl;
    if (t < nchunk)  chunk_cursor[t] = excl;
}

// K2 (fused): blocks [0,bblocks) bin edges; blocks [bblocks,...) do the dense
// transform via bf16 MFMA:
//   yb[n]    = bf16( x[n] @ W_lin^T )
//   selfb[n] = bf16( x[n] @ W_self^T + b_lin + b_self + bias )
// MFMA 16x16x32 bf16: A lane holds A[m=lane&15][k=quad*8+j]; B lane holds
// B[k=quad*8+j][n=lane&15] = W[o0+(lane&15)][f]; C/D col=lane&15,
// row=quad*4+reg (m89/m120). Both fragments load contiguous along f.
__global__ __launch_bounds__(256) void gcn_bin_transform_kernel(
    const int* __restrict__ src, const int* __restrict__ dst,
    int* __restrict__ chunk_cursor, int* __restrict__ bin_edges,
    const float* __restrict__ x,
    const float* __restrict__ W_lin,  const float* __restrict__ b_lin,
    const float* __restrict__ W_self, const float* __restrict__ b_self,
    const float* __restrict__ bias,
    unsigned short* __restrict__ yb, unsigned short* __restrict__ selfb,
    int n_nodes, int n_edges, int bblocks)
{
    __shared__ __align__(16) char smem[24592];   // binning branch only
    const int t = threadIdx.x;

    if ((int)blockIdx.x < bblocks) {
        // ---------------- binning branch ----------------
        int*           stage = (int*)smem;                        // [4096]
        unsigned char* cidx  = (unsigned char*)(smem + 16384);    // [4096]
        int*           h     = (int*)(smem + 20480);              // [256]
        int*           loff  = (int*)(smem + 21504);              // [256]
        int*           rc    = (int*)(smem + 22528);              // [256]
        int*           gbase = (int*)(smem + 23552);              // [256]
        int*           wsum  = (int*)(smem + 24576);              // [4]

        h[t] = 0; rc[t] = 0;
        __syncthreads();

        const int blo = blockIdx.x * BIN_T;
        const int cnt = min(BIN_T, n_edges - blo);

        int myc[16], mypk[16];
        #pragma unroll
        for (int k = 0; k < 16; ++k) {
            const int e = blo + k * 256 + t;
            if (e < n_edges) {
                const int d = dst[e];
                myc[k]  = d >> CH_BITS;
                mypk[k] = ((d & (CH_NODES - 1)) << 17) | src[e];
                atomicAdd(&h[myc[k]], 1);
            } else myc[k] = -1;
        }
        __syncthreads();

        const int v = h[t];
        if (v > 0) gbase[t] = atomicAdd(&chunk_cursor[t], v);
        const int incl = block_scan_incl256(v, t, wsum);
        loff[t] = incl - v;
        __syncthreads();

        #pragma unroll
        for (int k = 0; k < 16; ++k) {
            if (myc[k] >= 0) {
                const int p   = atomicAdd(&rc[myc[k]], 1);
                const int pos = loff[myc[k]] + p;
                stage[pos] = mypk[k];
                cidx[pos]  = (unsigned char)myc[k];
            }
        }
        __syncthreads();

        for (int i = t; i < cnt; i += 256) {
            const int c = cidx[i];
            bin_edges[gbase[c] + (i - loff[c])] = stage[i];
        }
        return;
    }

    // ---------------- MFMA transform branch (no LDS) ----------------
    const int lane = t & 63;
    const int wv   = t >> 6;
    const int idx  = lane & 15;       // node-in-tile (A) / out-feature-in-tile (B)
    const int quad = lane >> 4;       // k-quad
    const int node0 = ((int)blockIdx.x - bblocks) * NPB_T + wv * 64;
    if (node0 >= n_nodes) return;

    // W fragments: 4 o-tiles x 2 k-halves x 2 matrices, converted once per wave.
    short8 bl[4][2], bs[4][2];
    float bsum[4];
    #pragma unroll
    for (int ot = 0; ot < 4; ++ot) {
        const int o = ot * 16 + idx;
        bsum[ot] = b_lin[o] + b_self[o] + bias[o];
        #pragma unroll
        for (int h = 0; h < 2; ++h) {
            bl[ot][h] = frag8(&W_lin [o * 64 + h * 32 + quad * 8]);
            bs[ot][h] = frag8(&W_self[o * 64 + h * 32 + quad * 8]);
        }
    }

    for (int j = 0; j < 4; ++j) {                 // 4 node-tiles per wave
        const int tn0 = node0 + j * 16;
        if (tn0 >= n_nodes) break;
        const int rA = min(tn0 + idx, n_nodes - 1);     // load-clamp
        const short8 a0 = frag8(&x[(long long)rA * 64 + quad * 8]);
        const short8 a1 = frag8(&x[(long long)rA * 64 + 32 + quad * 8]);

        f32x4 accy[4], accs[4];
        #pragma unroll
        for (int ot = 0; ot < 4; ++ot) {
            accy[ot] = (f32x4){0.f, 0.f, 0.f, 0.f};
            accs[ot] = (f32x4){bsum[ot], bsum[ot], bsum[ot], bsum[ot]};
        }
        #pragma unroll
        for (int ot = 0; ot < 4; ++ot) {
            accy[ot] = __builtin_amdgcn_mfma_f32_16x16x32_bf16(a0, bl[ot][0], accy[ot], 0, 0, 0);
            accy[ot] = __builtin_amdgcn_mfma_f32_16x16x32_bf16(a1, bl[ot][1], accy[ot], 0, 0, 0);
            accs[ot] = __builtin_amdgcn_mfma_f32_16x16x32_bf16(a0, bs[ot][0], accs[ot], 0, 0, 0);
            accs[ot] = __builtin_amdgcn_mfma_f32_16x16x32_bf16(a1, bs[ot][1], accs[ot], 0, 0, 0);
        }
        // C/D: col(o-in-tile)=lane&15, row(node-in-tile)=quad*4+reg
        #pragma unroll
        for (int ot = 0; ot < 4; ++ot) {
            #pragma unroll
            for (int r = 0; r < 4; ++r) {
                const int n = tn0 + quad * 4 + r;
                if (n < n_nodes) {
                    yb   [(long long)n * 64 + ot * 16 + idx] = f2b(accy[ot][r]);
                    selfb[(long long)n * 64 + ot * 16 + idx] = f2b(accs[ot][r]);
                }
            }
        }
    }
}

// K3: per-chunk counting sort (in place) + node_start emission.
__global__ __launch_bounds__(256) void gcn_chunk_sort_kernel(
    int* __restrict__ bin_edges,
    const int* __restrict__ chunk_base,
    int* __restrict__ node_start, int n_nodes, int n_edges)
{
    __shared__ int stage[MAX_CHUNK_EDGES];   // 32 KB
    __shared__ int off[CH_NODES];
    __shared__ int cur[CH_NODES];
    __shared__ int wsum[4];

    const int b = blockIdx.x, t = threadIdx.x;
    const int lo  = chunk_base[b];
    const int cnt = min(chunk_base[b + 1] - lo, MAX_CHUNK_EDGES);

    for (int i = t; i < cnt; i += 256) stage[i] = bin_edges[lo + i];
    off[t] = 0; off[t + 256] = 0;
    __syncthreads();

    for (int i = t; i < cnt; i += 256) atomicAdd(&off[stage[i] >> 17], 1);
    __syncthreads();

    const int a0 = off[2 * t], a1 = off[2 * t + 1];
    const int incl = block_scan_incl256(a0 + a1, t, wsum);
    const int pexcl = incl - (a0 + a1);
    __syncthreads();
    off[2 * t] = pexcl;          off[2 * t + 1] = pexcl + a0;
    cur[2 * t] = pexcl;          cur[2 * t + 1] = pexcl + a0;

    const int n0 = b << CH_BITS;
    if (n0 + 2 * t     < n_nodes) node_start[n0 + 2 * t]     = lo + pexcl;
    if (n0 + 2 * t + 1 < n_nodes) node_start[n0 + 2 * t + 1] = lo + pexcl + a0;
    if (b == 0 && t == 0) node_start[n_nodes] = n_edges;
    __syncthreads();

    for (int i = t; i < cnt; i += 256) {
        const int p = stage[i];
        const int pos = atomicAdd(&cur[p >> 17], 1);
        bin_edges[lo + pos] = p & 0x1FFFF;
    }
}

// K4: per-node segment sum over bf16 y rows. One wave per node; 4 lane-groups
// of 16 x unroll 4 -> up to 4 independent row gathers in flight.
__global__ __launch_bounds__(256) void gcn_aggregate_kernel(
    const int* __restrict__ sorted_src, const int* __restrict__ node_start,
    const unsigned short* __restrict__ yb, const unsigned short* __restrict__ selfb,
    float* __restrict__ out, int n_nodes)
{
    const int node = ((int)blockIdx.x * 256 + threadIdx.x) >> 6;
    if (node >= n_nodes) return;
    const int lane = threadIdx.x & 63;
    const int grp = lane >> 4, sub = lane & 15;

    const int lo  = node_start[node];
    const int cnt = node_start[node + 1] - lo;

    float ax = 0.f, ay = 0.f, az = 0.f, aw = 0.f;
    for (int i = 0; i < cnt; i += 16) {
        bool val[4]; uint2 d[4];
        #pragma unroll
        for (int j = 0; j < 4; ++j) {
            const int k = i + grp + 4 * j;
            val[j] = k < cnt;
            const int s = val[j] ? sorted_src[lo + k] : 0;
            d[j] = *(const uint2*)(yb + ((long long)s << 6) + (sub << 2));
        }
        #pragma unroll
        for (int j = 0; j < 4; ++j) {
            if (val[j]) {
                ax += b2f_lo(d[j].x); ay += b2f_hi(d[j].x);
                az += b2f_lo(d[j].y); aw += b2f_hi(d[j].y);
            }
        }
    }
    ax += __shfl_xor(ax, 16); ay += __shfl_xor(ay, 16);
    az += __shfl_xor(az, 16); aw += __shfl_xor(aw, 16);
    ax += __shfl_xor(ax, 32); ay += __shfl_xor(ay, 32);
    az += __shfl_xor(az, 32); aw += __shfl_xor(aw, 32);

    if (grp == 0) {
        const uint2 sv = *(const uint2*)(selfb + ((long long)node << 6) + (sub << 2));
        float4 o;
        o.x = ax + b2f_lo(sv.x); o.y = ay + b2f_hi(sv.x);
        o.z = az + b2f_lo(sv.y); o.w = aw + b2f_hi(sv.y);
        *(float4*)(out + ((long long)node << 6) + (sub << 2)) = o;
    }
}

extern "C" void kernel_launch(void* const* d_in, const int* in_sizes, int n_in,
                              void* d_out, int out_size, void* d_ws, size_t ws_size,
                              hipStream_t stream) {
    const float* x      = (const float*)d_in[0];
    const int*   src    = (const int*)  d_in[1];
    const int*   dst    = (const int*)  d_in[2];
    const float* W_lin  = (const float*)d_in[3];
    const float* b_lin  = (const float*)d_in[4];
    const float* W_self = (const float*)d_in[5];
    const float* b_self = (const float*)d_in[6];
    const float* bias   = (const float*)d_in[7];

    float* out = (float*)d_out;

    const int n_nodes = in_sizes[0] / 64;
    const int n_edges = in_sizes[1];
    const int nchunk  = (n_nodes + CH_NODES - 1) >> CH_BITS;   // 196

    // ws layout: yb | selfb | bin_edges | node_start | chunk_cnt | done | chunk_base | chunk_cursor
    char* wsp = (char*)d_ws;
    unsigned short* yb    = (unsigned short*)wsp;
    unsigned short* selfb = (unsigned short*)(wsp + (size_t)n_nodes * 64 * 2);
    int* bin_edges    = (int*)(wsp + (size_t)n_nodes * 64 * 4);
    int* node_start   = bin_edges + n_edges;
    int* chunk_cnt    = node_start + n_nodes + 1;
    int* done         = chunk_cnt + 256;
    int* chunk_base   = done + 4;
    int* chunk_cursor = chunk_base + 257;

    const int hblocks = (n_edges + BIN_T - 1) / BIN_T;     // 313
    const int tblocks = (n_nodes + NPB_T - 1) / NPB_T;     // 391

    hipMemsetAsync(chunk_cnt, 0, 260 * 4, stream);
    gcn_hist_scan_kernel<<<hblocks, 256, 0, stream>>>(
        dst, chunk_cnt, done, chunk_base, chunk_cursor, n_edges, nchunk, hblocks);
    gcn_bin_transform_kernel<<<hblocks + tblocks, 256, 0, stream>>>(
        src, dst, chunk_cursor, bin_edges,
        x, W_lin, b_lin, W_self, b_self, bias,
        yb, selfb, n_nodes, n_edges, hblocks);
    gcn_chunk_sort_kernel<<<nchunk, 256, 0, stream>>>(
        bin_edges, chunk_base, node_start, n_nodes, n_edges);
    gcn_aggregate_kernel<<<(n_nodes + 3) / 4, 256, 0, stream>>>(
        bin_edges, node_start, yb, selfb, out, n_nodes);
}